// Round 3
// baseline (327.916 us; speedup 1.0000x reference)
//
#include <hip/hip_runtime.h>
#include <hip/hip_bf16.h>
#include <cstdint>

#define D_MODEL 2048
#define D_REC   384
#define NPROJ   1152          // 3*D_REC
#define BATCH   4
#define SEQ     4096
#define M_TOTAL (BATCH*SEQ)   // 16384
#define CHUNK   64
#define NCHUNK  (SEQ/CHUNK)   // 64

// GEMM v3 geometry: BM x BN chosen so grid = 64 x 4 = 256 blocks = 1/CU exactly.
#define BM 256
#define BN 288
#define BK 64
#define NTILE (D_MODEL/BK)    // 32 K-tiles

typedef __attribute__((ext_vector_type(8))) short  short8;
typedef __attribute__((ext_vector_type(4))) float  f32x4;

__device__ __forceinline__ float rcpf(float x) { return __builtin_amdgcn_rcpf(x); }

// ---------------------------------------------------------------- convert
__device__ __forceinline__ uint16_t f2bf(float x) {
    __hip_bfloat16 h = __float2bfloat16(x);
    return *reinterpret_cast<uint16_t*>(&h);
}

// one launch converts both x and W
__global__ void cvt_both(const float* __restrict__ x, uint16_t* __restrict__ xb,
                         const float* __restrict__ W, uint16_t* __restrict__ Wb) {
    const long nx = (long)M_TOTAL * D_MODEL;
    const long nw = (long)NPROJ * D_MODEL;
    long i = ((long)blockIdx.x * blockDim.x + threadIdx.x) * 4;
    if (i < nx) {
        float4 f = *reinterpret_cast<const float4*>(x + i);
        ushort4 o;
        o.x = f2bf(f.x); o.y = f2bf(f.y); o.z = f2bf(f.z); o.w = f2bf(f.w);
        *reinterpret_cast<ushort4*>(xb + i) = o;
    } else {
        long j = i - nx;
        if (j < nw) {
            float4 f = *reinterpret_cast<const float4*>(W + j);
            ushort4 o;
            o.x = f2bf(f.x); o.y = f2bf(f.y); o.z = f2bf(f.z); o.w = f2bf(f.w);
            *reinterpret_cast<ushort4*>(Wb + j) = o;
        }
    }
}

// ---------------------------------------------------------------- GEMM v3T
// C^T[n][m] = sum_k A[m][k]*B[n][k].  256x288 tile, BK=64, 8 waves (4M x 2N),
// per-wave 64x144 (acc 4x9 f32x4).  Grid 64x4 = 256 blocks = exactly 1/CU.
// Schedule identical to harness-verified v3 (88us, 0 bank conflicts).
// Epilogue writes the TRANSPOSED product aivT[n][m]: each lane's 4 acc values
// are 4 consecutive m at fixed n -> one float4 store, full 64B lines.
__device__ __forceinline__ void gload_lds16(const uint16_t* g, uint16_t* l) {
    __builtin_amdgcn_global_load_lds(
        (__attribute__((address_space(1))) void*)g,
        (__attribute__((address_space(3))) void*)l,
        16, 0, 0);
}

__launch_bounds__(512, 2)
__global__ void gemm_bf16nt_v3T(const uint16_t* __restrict__ A,   // [16384][2048]
                                const uint16_t* __restrict__ Bm,  // [1152][2048]
                                float* __restrict__ C)            // aivT [1152][16384]
{
    __shared__ __align__(16) uint16_t As[2][BM * BK];  // 2 x 32 KiB
    __shared__ __align__(16) uint16_t Bs[2][BN * BK];  // 2 x 36 KiB

    const int tid  = threadIdx.x;
    const int wave = tid >> 6;
    const int lane = tid & 63;
    const int m0 = blockIdx.x * BM;
    const int n0 = blockIdx.y * BN;
    const int wm = (wave >> 1) * 64;     // 4 M-waves
    const int wn = (wave & 1) * 144;     // 2 N-waves

    // ---- staging addressing (8 rows x 8 chunks per wave-call, swizzled src)
    const int rl = lane >> 3;            // 0..7 row within call
    const int cg = (lane & 7) ^ rl;      // swizzled 16B chunk
    const int ncb = (wave < 4) ? 5 : 4;
    const int cb0 = (wave < 4) ? wave * 5 : 20 + (wave - 4) * 4;
    const long aStage = (long)(m0 + wave * 32 + rl) * D_MODEL + cg * 8;
    const long bStage = (long)(n0 + cb0 * 8  + rl) * D_MODEL + cg * 8;

    // ---- fragment addressing
    const int lm = lane & 15;
    const int qq = lane >> 4;
    const int h  = lm & 7;

    f32x4 acc[4][9];
#pragma unroll
    for (int i = 0; i < 4; ++i)
#pragma unroll
        for (int j = 0; j < 9; ++j) acc[i][j] = (f32x4){0.f, 0.f, 0.f, 0.f};

    // ---- prologue: stage K-tile 0 into buf 0
    {
#pragma unroll
        for (int j = 0; j < 4; ++j)
            gload_lds16(A + aStage + (long)(8 * j) * D_MODEL,
                        &As[0][(wave * 32 + 8 * j) * 64]);
#pragma unroll
        for (int j = 0; j < 5; ++j)
            if (j < ncb)
                gload_lds16(Bm + bStage + (long)(8 * j) * D_MODEL,
                            &Bs[0][((cb0 + j) * 8) * 64]);
    }
    asm volatile("s_waitcnt vmcnt(0)" ::: "memory");
    __builtin_amdgcn_sched_barrier(0);
    __builtin_amdgcn_s_barrier();

    int buf = 0;
    for (int t = 0; t < NTILE; ++t) {
        // stage tile t+1 into the other buffer, issued FIRST for max latency cover
        if (t + 1 < NTILE) {
            const long k0 = (long)(t + 1) * BK;
            uint16_t* asb = &As[buf ^ 1][0];
            uint16_t* bsb = &Bs[buf ^ 1][0];
#pragma unroll
            for (int j = 0; j < 4; ++j)
                gload_lds16(A + aStage + k0 + (long)(8 * j) * D_MODEL,
                            asb + (wave * 32 + 8 * j) * 64);
#pragma unroll
            for (int j = 0; j < 5; ++j)
                if (j < ncb)
                    gload_lds16(Bm + bStage + k0 + (long)(8 * j) * D_MODEL,
                                bsb + ((cb0 + j) * 8) * 64);
            __builtin_amdgcn_sched_barrier(0);   // keep stages ahead of compute
        }

        const uint16_t* ap = &As[buf][0];
        const uint16_t* bp = &Bs[buf][0];
#pragma unroll
        for (int s = 0; s < 2; ++s) {
            short8 af[4], bfr[9];
#pragma unroll
            for (int mt = 0; mt < 4; ++mt)
                af[mt] = *reinterpret_cast<const short8*>(
                    &ap[(wm + mt * 16 + lm) * 64 + (((s * 4 + qq) ^ h) * 8)]);
#pragma unroll
            for (int nt = 0; nt < 9; ++nt)
                bfr[nt] = *reinterpret_cast<const short8*>(
                    &bp[(wn + nt * 16 + lm) * 64 + (((s * 4 + qq) ^ h) * 8)]);
            __builtin_amdgcn_s_setprio(1);
#pragma unroll
            for (int mt = 0; mt < 4; ++mt)
#pragma unroll
                for (int nt = 0; nt < 9; ++nt)
                    acc[mt][nt] = __builtin_amdgcn_mfma_f32_16x16x32_bf16(
                        af[mt], bfr[nt], acc[mt][nt], 0, 0, 0);
            __builtin_amdgcn_s_setprio(0);
        }

        if (t + 1 < NTILE) {
            asm volatile("s_waitcnt vmcnt(0)" ::: "memory");
            __builtin_amdgcn_sched_barrier(0);
            __builtin_amdgcn_s_barrier();
            buf ^= 1;
        }
    }

    // ---- epilogue (transposed): aivT[col][row..row+3] = acc  (one float4/lane)
#pragma unroll
    for (int mt = 0; mt < 4; ++mt) {
#pragma unroll
        for (int nt = 0; nt < 9; ++nt) {
            const int row = m0 + wm + mt * 16 + qq * 4;
            const int col = n0 + wn + nt * 16 + lm;
            float4 o;
            o.x = acc[mt][nt][0]; o.y = acc[mt][nt][1];
            o.z = acc[mt][nt][2]; o.w = acc[mt][nt][3];
            *reinterpret_cast<float4*>(&C[(long)col * M_TOTAL + row]) = o;
        }
    }
}

// ---------------------------------------------------------------- intra-chunk scan (t-PARALLEL)
// One wave per (b, chunk, d): lane = t.  Prefix product of clipped decay +
// prefix sum of sig/cumdec via 6 shfl_up steps each (replaces the 64-step
// serial loop).  All global accesses are 256B/wave contiguous (transposed
// layout).  Semantics identical to the serial version (association order of
// the product differs at ULP level only; clip/underflow behavior preserved).
__global__ void intra_scan_T(const float* __restrict__ aivT, const float* __restrict__ bias,
                             float* __restrict__ cumwT,   // [NPROJ? no: D_REC][M_TOTAL] slabs
                             float* __restrict__ cumdecT, // [D_REC][M_TOTAL]
                             float* __restrict__ ctd,     // [B][NCHUNK][D]
                             float* __restrict__ cfs)     // [B][NCHUNK][D]
{
    const int w = threadIdx.x >> 6;          // 0..3
    const int t = threadIdx.x & 63;          // time step within chunk
    const int d = blockIdx.z * 4 + w;        // 0..383
    const int c = blockIdx.x;
    const int b = blockIdx.y;
    const long m = (long)b * SEQ + (long)c * CHUNK + t;

    const float ap = aivT[(long)d * M_TOTAL + m];
    const float ip = aivT[(long)(D_REC + d) * M_TOTAL + m];
    const float vv = aivT[(long)(2 * D_REC + d) * M_TOTAL + m];

    const float a   = rcpf(1.f + __expf(-(ap + bias[d])));
    const float g   = rcpf(1.f + __expf(-ip));
    const float sig = sqrtf(fmaxf(1.f - a * a, 1e-8f)) * (g * vv);

    // inclusive prefix product of clipped decay
    float cd = fmaxf(a, 1e-10f);
#pragma unroll
    for (int off = 1; off < 64; off <<= 1) {
        const float o = __shfl_up(cd, off, 64);
        cd = (t >= off) ? cd * o : cd;
    }
    // inclusive prefix sum of sig / clip(cd)
    float cw = sig * rcpf(fmaxf(cd, 1e-10f));
#pragma unroll
    for (int off = 1; off < 64; off <<= 1) {
        const float o = __shfl_up(cw, off, 64);
        cw = (t >= off) ? cw + o : cw;
    }

    cumdecT[(long)d * M_TOTAL + m] = cd;
    cumwT [(long)d * M_TOTAL + m] = cw;
    if (t == 63) {
        const long cb = ((long)b * NCHUNK + c) * D_REC + d;
        ctd[cb] = cd;
        cfs[cb] = cd * cw;
    }
}

// ---------------------------------------------------------------- cross-chunk scan
__global__ void cross_scan(const float* __restrict__ ctd, const float* __restrict__ cfs,
                           float* __restrict__ incoming)  // [B][NCHUNK][D]
{
    const int d = threadIdx.x;
    const int b = blockIdx.x;
    float cdk = 1.f, cwk = 0.f;
    incoming[(long)b * NCHUNK * D_REC + d] = 0.f;
#pragma unroll 4
    for (int c = 0; c < NCHUNK; ++c) {
        const long idx = ((long)b * NCHUNK + c) * D_REC + d;
        const float td = ctd[idx];
        const float fs = cfs[idx];
        cdk *= fmaxf(td, 1e-10f);
        cwk += fs * rcpf(fmaxf(cdk, 1e-10f));
        if (c + 1 < NCHUNK) incoming[idx + D_REC] = cdk * cwk;
    }
}

// ---------------------------------------------------------------- final combine + transpose
// out[b][s][d] = cumdecT[d][m] * (cumwT[d][m] + inc[m/64][d]),  m = b*4096+s.
// 64x64 tile through padded LDS: reads coalesced in m, writes coalesced in d.
__global__ void final_combine_T(const float* __restrict__ cumdecT, const float* __restrict__ cumwT,
                                const float* __restrict__ inc, float* __restrict__ out)
{
    __shared__ float tile[64][65];
    const int m0 = blockIdx.x * 64;            // 256 tiles over m (one chunk each)
    const int d0 = blockIdx.y * 64;            // 6 tiles over d
    const long incBase = (long)(m0 >> 6) * D_REC + d0;   // (b*64+c)*384 + d0

#pragma unroll
    for (int i = 0; i < 16; ++i) {
        const int flat = threadIdx.x + i * 256;
        const int dd = flat >> 6, ss = flat & 63;
        const long src = (long)(d0 + dd) * M_TOTAL + m0 + ss;
        tile[dd][ss] = cumdecT[src] * (cumwT[src] + inc[incBase + dd]);
    }
    __syncthreads();
#pragma unroll
    for (int i = 0; i < 16; ++i) {
        const int flat = threadIdx.x + i * 256;
        const int ss = flat >> 6, dd = flat & 63;
        out[(long)(m0 + ss) * D_REC + d0 + dd] = tile[dd][ss];
    }
}

// ---------------------------------------------------------------- launch
extern "C" void kernel_launch(void* const* d_in, const int* in_sizes, int n_in,
                              void* d_out, int out_size, void* d_ws, size_t ws_size,
                              hipStream_t stream) {
    const float* x  = (const float*)d_in[0];   // [4][4096][2048]
    const float* W  = (const float*)d_in[1];   // [1152][2048]
    const float* db = (const float*)d_in[2];   // [384]
    float* out = (float*)d_out;                // [4][4096][384]

    char* ws = (char*)d_ws;
    // layout (bytes): aivT 75.5MB | xb 64MB (dead after GEMM; cumdecT+cumwT overlay) | Wb 4.5MB
    float*    aivT    = (float*)   (ws + 0);                 // 75,497,472 B  [1152][16384]
    uint16_t* xb      = (uint16_t*)(ws + 75497472L);         // 67,108,864 B
    uint16_t* Wb      = (uint16_t*)(ws + 142606336L);        //  4,718,592 B
    float*    cumdecT = (float*)   (ws + 75497472L);         // 25,165,824 B (overlays xb)
    float*    cumwT   = (float*)   (ws + 100663296L);        // 25,165,824 B (overlays xb)
    float*    ctd     = (float*)   (ws + 125829120L);        //    393,216 B
    float*    cfs     = (float*)   (ws + 126222336L);        //    393,216 B
    float*    inc     = (float*)   (ws + 126615552L);        //    393,216 B

    // 1. convert x and W to bf16 (single launch)
    {
        const long ntot = (long)M_TOTAL * D_MODEL + (long)NPROJ * D_MODEL;
        cvt_both<<<(int)((ntot + 1023) / 1024), 256, 0, stream>>>(x, xb, W, Wb);
    }

    // 2. aivT = (x . W^T)^T via bf16 MFMA (256x288 tile, 8 waves, 1 block/CU)
    gemm_bf16nt_v3T<<<dim3(M_TOTAL / BM, NPROJ / BN), 512, 0, stream>>>(xb, Wb, aivT);

    // 3. intra-chunk scan, wave-parallel over t (one wave per (b,c,d))
    intra_scan_T<<<dim3(NCHUNK, BATCH, D_REC / 4), 256, 0, stream>>>(aivT, db, cumwT, cumdecT, ctd, cfs);

    // 4. cross-chunk scan
    cross_scan<<<BATCH, D_REC, 0, stream>>>(ctd, cfs, inc);

    // 5. combine + transpose back to [B][S][D]
    final_combine_T<<<dim3(M_TOTAL / 64, D_REC / 64), 256, 0, stream>>>(cumdecT, cumwT, inc, out);
}